// Round 1
// baseline (103.608 us; speedup 1.0000x reference)
//
#include <hip/hip_runtime.h>
#include <math.h>

#define BB 2
#define NN 1024
#define F_IN 128
#define HH 4
#define HID 32
#define TI 8      // query rows per block (one per wave)
#define TJ 64     // j-tile size (one j per lane)
#define NT (NN/TJ)

// ---------------- Kernel 1: projection x[b][h][n][k] = sum_f feat[b][n][f] * W[f][h*HID+k]
__global__ __launch_bounds__(128) void gat_proj_kernel(const float* __restrict__ feat,
                                                       const float* __restrict__ W,
                                                       float* __restrict__ xout) {
    const int RPB = 8; // node rows per block
    int blk = blockIdx.x;             // 0 .. B*N/RPB-1
    int b  = blk / (NN / RPB);
    int n0 = (blk % (NN / RPB)) * RPB;
    int t  = threadIdx.x;             // 0..127 -> output column c = h*HID+k

    __shared__ float fs[RPB][F_IN];
    for (int e = t; e < RPB * F_IN; e += 128) {
        int r = e >> 7;       // /128
        int f = e & 127;
        fs[r][f] = feat[((size_t)(b * NN + n0 + r)) * F_IN + f];
    }
    __syncthreads();

    float acc[RPB];
#pragma unroll
    for (int r = 0; r < RPB; ++r) acc[r] = 0.f;

    for (int f = 0; f < F_IN; ++f) {
        float w = W[f * (HH * HID) + t];
#pragma unroll
        for (int r = 0; r < RPB; ++r) acc[r] = fmaf(fs[r][f], w, acc[r]);
    }

    int h = t / HID, k = t % HID;
#pragma unroll
    for (int r = 0; r < RPB; ++r)
        xout[(((size_t)(b * HH + h)) * NN + (n0 + r)) * HID + k] = acc[r];
}

// ---------------- Kernel 2: fused GATv2 attention (scores + masked online softmax + aggregate)
__global__ __launch_bounds__(512) void gat_attn_kernel(const float* __restrict__ x,   // (B,H,N,HID)
                                                       const int*   __restrict__ adj, // (B,N,N)
                                                       const float* __restrict__ Wa,  // (H,HID)
                                                       float* __restrict__ out)       // (B,N,H*HID)
{
    int blk = blockIdx.x;                 // 0 .. B*H*N/TI - 1
    int i0  = (blk % (NN / TI)) * TI;
    int bh  = blk / (NN / TI);
    int h   = bh % HH;
    int b   = bh / HH;
    int tid = threadIdx.x;
    int w   = tid >> 6;      // wave id 0..7
    int l   = tid & 63;      // lane
    int i   = i0 + w;        // this wave's query row

    __shared__ float xs[TJ][HID + 1];   // 64 x 33 (pad -> conflict-free)
    __shared__ float ps[TI][TJ];        // per-wave p values

    const float* xbh = x + ((size_t)(b * HH + h)) * NN * HID;
    const int* adjrow = adj + ((size_t)b * NN + i) * NN;

    // hoist Wa and x_i into registers (static indices via full unroll)
    float wa[HID], xi[HID];
#pragma unroll
    for (int k = 0; k < HID; ++k) wa[k] = Wa[h * HID + k];
#pragma unroll
    for (int k = 0; k < HID; ++k) xi[k] = xbh[(size_t)i * HID + k];

    float m_run = -INFINITY;
    float l_run = 0.f;
    float acc   = 0.f;       // lane l accumulates out[k = l&31] over its j-half
    int   kk    = l & 31;
    int   half  = l >> 5;

    for (int t = 0; t < NT; ++t) {
        int j0 = t * TJ;
        __syncthreads();  // protect previous tile's xs reads
        // cooperative stage: 64 rows x 32 floats, 512 threads -> 4 elems each, coalesced
#pragma unroll
        for (int e = 0; e < (TJ * HID) / 512; ++e) {
            int idx = e * 512 + tid;
            int jj = idx >> 5;
            int kx = idx & 31;
            xs[jj][kx] = xbh[(size_t)(j0 + jj) * HID + kx];
        }
        __syncthreads();

        // ---- score for j = j0 + l
        int a = adjrow[j0 + l];
        float e_s = 0.f;
#pragma unroll
        for (int k = 0; k < HID; ++k) {
            float v = xi[k] + xs[l][k];
            v = fmaxf(v, 0.2f * v);          // leaky_relu(0.2)
            e_s = fmaf(v, wa[k], e_s);
        }
        if (a <= 0) e_s = -INFINITY;

        // ---- wave-wide max
        float mt = e_s;
#pragma unroll
        for (int off = 32; off >= 1; off >>= 1)
            mt = fmaxf(mt, __shfl_xor(mt, off, 64));
        float m_new = fmaxf(m_run, mt);

        float scale, p;
        if (m_new == -INFINITY) { scale = 1.f; p = 0.f; }
        else {
            scale = __expf(m_run - m_new);              // m_run=-inf -> 0
            p = (a <= 0) ? 0.f : __expf(e_s - m_new);
        }

        float psum = p;
#pragma unroll
        for (int off = 32; off >= 1; off >>= 1)
            psum += __shfl_xor(psum, off, 64);
        l_run = l_run * scale + psum;
        m_run = m_new;

        ps[w][l] = p;   // intra-wave LDS RAW; compiler inserts lgkmcnt wait

        // ---- aggregate: lane (half,kk) does sum over its 32 j's
        acc *= scale;
#pragma unroll
        for (int jj = 0; jj < 32; ++jj) {
            int j = half * 32 + jj;
            acc = fmaf(ps[w][j], xs[j][kk], acc);
        }
    }

    // combine the two j-halves and normalize
    float other = __shfl_xor(acc, 32, 64);
    float tot = acc + other;
    if (half == 0) {
        out[((size_t)(b * NN + i)) * (HH * HID) + h * HID + kk] = tot / l_run;
    }
}

extern "C" void kernel_launch(void* const* d_in, const int* in_sizes, int n_in,
                              void* d_out, int out_size, void* d_ws, size_t ws_size,
                              hipStream_t stream) {
    const float* node_feat = (const float*)d_in[0];
    const int*   adj_mtx   = (const int*)d_in[1];
    const float* W         = (const float*)d_in[2];
    const float* Wa        = (const float*)d_in[3];
    float* out = (float*)d_out;
    float* x_ws = (float*)d_ws;   // (B,H,N,HID) fp32 = 1 MB

    // projection
    dim3 g1(BB * NN / 8), b1(128);
    hipLaunchKernelGGL(gat_proj_kernel, g1, b1, 0, stream, node_feat, W, x_ws);

    // fused attention
    dim3 g2(BB * HH * NN / TI), b2(512);
    hipLaunchKernelGGL(gat_attn_kernel, g2, b2, 0, stream, x_ws, adj_mtx, Wa, out);
}